// Round 11
// baseline (1330.484 us; speedup 1.0000x reference)
//
#include <hip/hip_runtime.h>

// Liquid NN: BATCH=64, SEQ=256, IN=512, HID=1024, 2 layers, tau=0.5.
// h0(t) = h0 + a0*2*(tanh(x_t@W0^T + b0 + h0@U0^T) - h0)
// h1(t) = h1 + a1*2*(tanh(h0(t)@W1^T + b1 + h1@U1^T) - h1)
// Output: h1(255) as f32 (64,1024).
//
// R15 = R13 (batch-split, 1199us, validated) + two safe fixes:
//  (1) FLAG-WORD sync (R4/R6-validated primitives) instead of shared counters:
//      R13's 16 fetch_adds on ONE word serialize ~16 RMWs at the MALL on the
//      critical chain. Per-WG flag words publish with a single relaxed AGENT
//      STORE (no RMW, no serialization); consumers poll a full 64B line with
//      a 16-lane vector load (R6), barrier-free per-wave FULL-condition polls
//      (R10-validated; R5's bug was partial-condition wave-local slices).
//      Algebra (depth-8 rings, identical to R6/R13):
//        role0 s: flag0w[*]>=s (peers s-1), flag1w[*]>=s-7 (ring slot free)
//        role1 t: flag0w[*]>=t+1 (h0(t) ready), flag1w[*]>=t (peers + ring)
//        publish: tid0 stores flagXw[slice]=step+1 AFTER the drain barrier.
//  (2) LDS stride 64->68 in the reduce buffer: R13's 6.3M bank conflicts are
//      the stride-64 reduce-read (start bank = bcol%32, 8 values -> 8-way).
//      At stride 68 the start-bank histogram is uniform (8 lanes/start) =
//      the 8-phase LDS floor, zero conflicts. Map identity unaffected.
// R14 WGRP/sc0 substrate REVERTED (absmax 0.24; unproven coherence mechanism).
//
// Kept from R13 (validated): 4 groups x 16 rows on 4 XCDs, 256-block grid
// (32/XCD pigeonhole election), depth-8 rings, per-wave full polls, no l1_inv
// (capacity argument), NT wx loads, fast exp tanh, 16-row XOR LDS reduce map,
// k_wx @2048 blocks, 1 WG/CU (no occupancy cap).

typedef _Float16 f16;
typedef _Float16 f16x4 __attribute__((ext_vector_type(4)));
typedef _Float16 f16x8 __attribute__((ext_vector_type(8)));
typedef float    f32x4 __attribute__((ext_vector_type(4)));

#define B_  64
#define S_  256
#define IN_ 512
#define H_  1024
#define GR_ 16   // batch rows per group

static constexpr size_t OFF_WX  = 0;         // S*B*H f16 = 33554432
static constexpr size_t OFF_H0R = 33554432;  // 4 groups x 8*16*H f16 = 1048576
static constexpr size_t OFF_H1R = 34603008;  // 4 groups x 8*16*H f16 = 1048576
static constexpr size_t OFF_FLG = 35651584;  // sync area (memset 32768 B)
// flg ints: group g (stride 256 ints = 1KB):
//   flag0w[16] @ g*256 (64B line), flag1w[16] @ g*256+16 (next 64B line)
// election: ecnt[8] @ 1024, xgrp[8] @ 1032

#define AGENT __HIP_MEMORY_SCOPE_AGENT

// ---------------- kernel: Wx = x @ W0^T + b0 (f32 in, f16 out) ----------------
__global__ __launch_bounds__(256) void k_wx(const float* __restrict__ x,
                                            const float* __restrict__ W0,
                                            const float* __restrict__ b0,
                                            f16* __restrict__ wx) {
  __shared__ uint4 xs[4096];  // 64 rows x 64 8-half chunks, chunk' = kc ^ (row&7)
  const int tid = threadIdx.x;
  const int w = tid >> 6, lane = tid & 63;
  const int q = lane >> 4, l15 = lane & 15;
  const int cslice = blockIdx.x & 15;
  const int rblock = blockIdx.x >> 4;  // 0..127
  const int c = cslice * 64 + w * 16 + l15;

  f16x8 Bf[16];  // B[k][n] = W0[c][k], lane holds k = kf*32 + q*8 + j
#pragma unroll
  for (int kf = 0; kf < 16; ++kf) {
    const float* p = W0 + (size_t)c * IN_ + kf * 32 + q * 8;
    f16x8 v;
#pragma unroll
    for (int j = 0; j < 8; ++j) v[j] = (f16)p[j];
    Bf[kf] = v;
  }
  const float bias = b0[c];

  for (int rt = 0; rt < 2; ++rt) {
    const int row0 = rblock * 128 + rt * 64;
    __syncthreads();
#pragma unroll
    for (int it = 0; it < 16; ++it) {
      int g = it * 256 + tid;
      int r = g >> 6, kc = g & 63;
      const float* xp = x + (size_t)(row0 + r) * IN_ + kc * 8;
      float4 v0 = *(const float4*)xp;
      float4 v1 = *(const float4*)(xp + 4);
      f16x8 h;
      h[0] = (f16)v0.x; h[1] = (f16)v0.y; h[2] = (f16)v0.z; h[3] = (f16)v0.w;
      h[4] = (f16)v1.x; h[5] = (f16)v1.y; h[6] = (f16)v1.z; h[7] = (f16)v1.w;
      xs[r * 64 + (kc ^ (r & 7))] = *(uint4*)&h;
    }
    __syncthreads();
    f32x4 acc[4] = {};
#pragma unroll
    for (int mt = 0; mt < 4; ++mt) {
      const int r = mt * 16 + l15;
#pragma unroll
      for (int kf = 0; kf < 16; ++kf) {
        uint4 av = xs[r * 64 + ((kf * 4 + q) ^ (r & 7))];
        f16x8 a = *(f16x8*)&av;
        acc[mt] = __builtin_amdgcn_mfma_f32_16x16x32_f16(a, Bf[kf], acc[mt], 0, 0, 0);
      }
    }
#pragma unroll
    for (int mt = 0; mt < 4; ++mt) {
#pragma unroll
      for (int r = 0; r < 4; ++r) {
        int rowg = row0 + mt * 16 + q * 4 + r;  // = b*256 + t
        int b = rowg >> 8, t = rowg & 255;
        wx[((size_t)t * B_ + b) * H_ + c] = (f16)(acc[mt][r] + bias);
      }
    }
  }
}

// ---------------- persistent recurrent kernel ----------------
// dual flag-line poll, per-wave FULL condition: lanes 0-15 wait fA[lane]>=tA,
// lanes 16-31 wait fB[lane&15]>=tB. Each line is one 64B vector load per
// round trip (R6-validated); publishes are plain stores so no RMW queue.
__device__ __forceinline__ void pollf2(const int* fA, int tA,
                                       const int* fB, int tB, int lane) {
  const bool a = (lane < 16) && (tA > 0);
  const bool b = (lane >= 16) && (lane < 32) && (tB > 0);
  const int* p = a ? (fA + lane) : (fB + (lane & 15));
  const int tgt = a ? tA : tB;
  bool pend = a || b;
  if (pend && __hip_atomic_load((int*)p, __ATOMIC_RELAXED, AGENT) >= tgt)
    pend = false;
  while (__ballot(pend)) {
    __builtin_amdgcn_s_sleep(2);
    if (pend && __hip_atomic_load((int*)p, __ATOMIC_RELAXED, AGENT) >= tgt)
      pend = false;
  }
}

// fast tanh: t = e^{-2|x|} in (0,1], tanh = sign(x)*(1-t)/(1+t). ~1e-7 abs err.
__device__ __forceinline__ float fast_tanh(float x) {
  float t = __expf(-2.0f * fabsf(x));
  float r = (1.0f - t) / (1.0f + t);
  return copysignf(r, x);
}

// 16-row slab: M=16 (one MFMA m-tile), 64 cols, K=256 per wave. ONE batch of
// 8 b128 loads (all in flight immediately) + 32 MFMA.
__device__ __forceinline__ void slab16(const f16* __restrict__ A, int kbase,
                                       int l15, int q,
                                       const f16x8 (&Bf)[4][8], f32x4 (&acc)[4]) {
  f16x8 cur[8];
  const f16* ar = A + (size_t)l15 * H_ + kbase + q * 8;
#pragma unroll
  for (int kf = 0; kf < 8; ++kf) cur[kf] = *(const f16x8*)(ar + kf * 32);
#pragma unroll
  for (int nt = 0; nt < 4; ++nt)
#pragma unroll
    for (int kf = 0; kf < 8; ++kf)
      acc[nt] = __builtin_amdgcn_mfma_f32_16x16x32_f16(cur[kf], Bf[nt][kf],
                                                       acc[nt], 0, 0, 0);
}

__global__ __launch_bounds__(256, 1) void k_persist(
    const float* __restrict__ U0, const float* __restrict__ W1,
    const float* __restrict__ U1, const float* __restrict__ alpha0,
    const float* __restrict__ alpha1, const float* __restrict__ b1,
    const f16* __restrict__ wx, f16* h0r, f16* h1r, int* flg, float* out) {
  // red[ks][i][col]: wave ks's D (16x64) + 4-col pad. i = nt*4 + r,
  // col' = lane ^ (r<<2). STRIDE 68: reduce-read start bank becomes
  // (iidx*4 + bcol)%32 -> uniform histogram, 8 lanes/start = LDS floor,
  // zero conflicts (stride 64 gave 8-way: 6.3M SQ_LDS_BANK_CONFLICT in R13).
  __shared__ __attribute__((aligned(16))) float red[4][16][68];  // 17 KiB
  const int tid = threadIdx.x;
  const int w = tid >> 6, lane = tid & 63;
  const int q = lane >> 4, l15 = lane & 15;

  int* ecnt = flg + 1024;  // per-XCD arrival tickets
  int* xgrp = flg + 1032;  // per-XCD group assignment: 0=pending, g+1, or -1

  // ---- election: 4 XCDs x 32 workers. 256 blocks = exactly 32/XCD resident
  // (validated); block 0 claims the first 4 full XCDs. AGENT scope (cross-XCD).
  const int xcc = (int)__builtin_amdgcn_s_getreg(6164) & 7;  // HW_REG_XCC_ID
  int* sh = (int*)&red[0][0][0];
  if (tid == 0) {
    int my = __hip_atomic_fetch_add(ecnt + xcc, 1, __ATOMIC_RELAXED, AGENT);
    if (blockIdx.x == 0) {
      unsigned taken = 0; int assigned = 0;
      while (assigned < 4) {
        for (int i = 0; i < 8 && assigned < 4; ++i)
          if (!((taken >> i) & 1) &&
              __hip_atomic_load(ecnt + i, __ATOMIC_RELAXED, AGENT) >= 32) {
            taken |= 1u << i;
            __hip_atomic_store(xgrp + i, assigned + 1, __ATOMIC_RELAXED, AGENT);
            ++assigned;
          }
        if (assigned < 4) __builtin_amdgcn_s_sleep(1);
      }
      for (int i = 0; i < 8; ++i)
        if (!((taken >> i) & 1))
          __hip_atomic_store(xgrp + i, -1, __ATOMIC_RELAXED, AGENT);
    }
    int grp = -1;
    if (my < 32) {
      int v;
      while ((v = __hip_atomic_load(xgrp + xcc, __ATOMIC_RELAXED, AGENT)) == 0)
        __builtin_amdgcn_s_sleep(1);
      if (v > 0) grp = v - 1;
    }
    sh[0] = (grp >= 0) ? my : -1;
    sh[1] = grp;
  }
  __syncthreads();
  const int myid = sh[0], g = sh[1];
  __syncthreads();
  if (myid < 0) return;
  const int role = myid >> 4, slice = myid & 15;
  const int c0 = slice * 64;
  const int kbase = w * 256;

  int* flag0w = flg + g * 256;       // word j = steps completed by role0 WG j
  int* flag1w = flg + g * 256 + 16;  // word j = steps completed by role1 WG j
  f16* h0g = h0r + (size_t)g * 8 * GR_ * H_;  // group's depth-8 rings
  f16* h1g = h1r + (size_t)g * 8 * GR_ * H_;

  // ---- weight slices into registers: B[k][n] = Wm[c][k] ----
  f16x8 BfA[4][8];  // role0: U0 ; role1: W1
  f16x8 BfB[4][8];  // role1: U1
  {
    const float* WmA = (role == 0) ? U0 : W1;
#pragma unroll
    for (int nt = 0; nt < 4; ++nt)
#pragma unroll
      for (int kf = 0; kf < 8; ++kf) {
        const float* p = WmA + (size_t)(c0 + nt * 16 + l15) * H_ + kbase + kf * 32 + q * 8;
        f16x8 v;
#pragma unroll
        for (int j = 0; j < 8; ++j) v[j] = (f16)p[j];
        BfA[nt][kf] = v;
      }
    if (role == 1) {
#pragma unroll
      for (int nt = 0; nt < 4; ++nt)
#pragma unroll
        for (int kf = 0; kf < 8; ++kf) {
          const float* p = U1 + (size_t)(c0 + nt * 16 + l15) * H_ + kbase + kf * 32 + q * 8;
          f16x8 v;
#pragma unroll
          for (int j = 0; j < 8; ++j) v[j] = (f16)p[j];
          BfB[nt][kf] = v;
        }
    }
  }

  // ---- epilogue ownership: thread owns (row16, 4 cols) — coalesced stores.
  const int row16 = tid >> 4, cgrp = tid & 15;
  const int iidx  = (cgrp >> 2) * 4 + (row16 & 3);
  const int bcol  = (row16 >> 2) * 16 + ((((cgrp & 3) * 4)) ^ ((row16 & 3) << 2));
  const int coff  = c0 + cgrp * 4;   // global col base of the 4 owned cols
  const int bglob = g * GR_ + row16; // global batch row

  float cf[4], bs[4];
  {
    const float* ap = ((role == 0) ? alpha0 : alpha1) + coff;
    const float* bp = b1 + coff;
#pragma unroll
    for (int j = 0; j < 4; ++j) { cf[j] = ap[j] * 2.0f; bs[j] = bp[j]; }
  }

  float hst[4] = {0.f, 0.f, 0.f, 0.f};

  if (role == 0) {
    for (int s = 0; s < 256; ++s) {
      // NT wx prefetch (8 B/thread, coalesced), in flight during the poll.
      const f16* wp = wx + ((size_t)s * B_ + bglob) * H_ + coff;
      f16x4 wxv = __builtin_nontemporal_load((const f16x4*)wp);
      f32x4 acc[4] = {};
      if (s > 0) {
        // peers' h0(s-1): flag0w[*]>=s ; ring slot s&7 free: flag1w[*]>=s-7
        pollf2(flag0w, s, flag1w, s - 7, lane);
        slab16(h0g + (size_t)((s - 1) & 7) * GR_ * H_, kbase, l15, q, BfA, acc);
      }
#pragma unroll
      for (int nt = 0; nt < 4; ++nt)
#pragma unroll
        for (int r = 0; r < 4; ++r)
          red[w][nt * 4 + r][lane ^ (r << 2)] = acc[nt][r];
      __syncthreads();
      f32x4 vs = {};
#pragma unroll
      for (int ks = 0; ks < 4; ++ks) {
        f32x4 v = *(const f32x4*)&red[ks][iidx][bcol];
        vs[0] += v[0]; vs[1] += v[1]; vs[2] += v[2]; vs[3] += v[3];
      }
      f16* hw = h0g + (size_t)(s & 7) * GR_ * H_ + (size_t)row16 * H_ + coff;
      f16x4 o;
#pragma unroll
      for (int j = 0; j < 4; ++j) {
        float th = fast_tanh(vs[j] + (float)wxv[j]);
        float h = hst[j];
        h = h + cf[j] * (th - h);
        hst[j] = h;
        o[j] = (f16)h;
      }
      *(f16x4*)hw = o;
      __syncthreads();  // drain h stores to L2 + fence red reuse
      if (tid == 0)
        __hip_atomic_store(flag0w + slice, s + 1, __ATOMIC_RELAXED, AGENT);
    }
  } else {
    for (int t = 0; t < 256; ++t) {
      // h0(t) ready: flag0w[*]>=t+1 ; peers' h1(t-1) + ring: flag1w[*]>=t
      pollf2(flag0w, t + 1, flag1w, t, lane);
      f32x4 acc[4] = {};
      // both A batches issued up front (16 b128 in flight), then MFMAs.
      f16x8 cA[8], cB[8];
      const f16* a0 = h0g + (size_t)(t & 7) * GR_ * H_ + (size_t)l15 * H_ + kbase + q * 8;
#pragma unroll
      for (int kf = 0; kf < 8; ++kf) cA[kf] = *(const f16x8*)(a0 + kf * 32);
      if (t > 0) {
        const f16* a1 = h1g + (size_t)((t - 1) & 7) * GR_ * H_ + (size_t)l15 * H_ + kbase + q * 8;
#pragma unroll
        for (int kf = 0; kf < 8; ++kf) cB[kf] = *(const f16x8*)(a1 + kf * 32);
      }
#pragma unroll
      for (int nt = 0; nt < 4; ++nt)
#pragma unroll
        for (int kf = 0; kf < 8; ++kf)
          acc[nt] = __builtin_amdgcn_mfma_f32_16x16x32_f16(cA[kf], BfA[nt][kf],
                                                           acc[nt], 0, 0, 0);
      if (t > 0) {
#pragma unroll
        for (int nt = 0; nt < 4; ++nt)
#pragma unroll
          for (int kf = 0; kf < 8; ++kf)
            acc[nt] = __builtin_amdgcn_mfma_f32_16x16x32_f16(cB[kf], BfB[nt][kf],
                                                             acc[nt], 0, 0, 0);
      }
#pragma unroll
      for (int nt = 0; nt < 4; ++nt)
#pragma unroll
        for (int r = 0; r < 4; ++r)
          red[w][nt * 4 + r][lane ^ (r << 2)] = acc[nt][r];
      __syncthreads();
      f32x4 vs = {};
#pragma unroll
      for (int ks = 0; ks < 4; ++ks) {
        f32x4 v = *(const f32x4*)&red[ks][iidx][bcol];
        vs[0] += v[0]; vs[1] += v[1]; vs[2] += v[2]; vs[3] += v[3];
      }
      f16* hw = h1g + (size_t)(t & 7) * GR_ * H_ + (size_t)row16 * H_ + coff;
      f16x4 o;
#pragma unroll
      for (int j = 0; j < 4; ++j) {
        float th = fast_tanh(vs[j] + bs[j]);
        float h = hst[j];
        h = h + cf[j] * (th - h);
        hst[j] = h;
        o[j] = (f16)h;
      }
      *(f16x4*)hw = o;
      if (t == 255) {
        float* op = out + (size_t)bglob * H_ + coff;
        float4 vv;
        vv.x = hst[0]; vv.y = hst[1]; vv.z = hst[2]; vv.w = hst[3];
        *(float4*)op = vv;
      }
      __syncthreads();  // drain h1 stores + fence red reuse
      if (tid == 0)
        __hip_atomic_store(flag1w + slice, t + 1, __ATOMIC_RELAXED, AGENT);
    }
  }
}

// LDS map identity (16-row variant): writer wave ks, lane = q*16+l15 stores
// D[m][n] (m=q*4+r, n=nt*16+l15) at red[ks][nt*4+r][(q*16+l15)^(r<<2)].
// Reader (row16,cgrp) wants (m=row16, n=cgrp*4+j): r=row16&3, nt=cgrp>>2,
// q=row16>>2, l15=(cgrp&3)*4+j -> i=nt*4+r, col'=q*16+(((cgrp&3)*4+j)^(r<<2)).
// XOR touches bits 2-3 only, j lives in bits 0-1 -> col' = bcol + j: one
// aligned f32x4 read. (row16,cgrp)->(i,bcol) is bijective over 256 threads.
// Stride 68: read start-bank = (iidx*4 + bcol)%32 -> uniform, zero conflicts.

extern "C" void kernel_launch(void* const* d_in, const int* in_sizes, int n_in,
                              void* d_out, int out_size, void* d_ws, size_t ws_size,
                              hipStream_t stream) {
  const float* x  = (const float*)d_in[0];
  const float* W0 = (const float*)d_in[1];
  const float* U0 = (const float*)d_in[2];
  const float* b0 = (const float*)d_in[3];
  const float* a0 = (const float*)d_in[4];
  const float* W1 = (const float*)d_in[5];
  const float* U1 = (const float*)d_in[6];
  const float* b1 = (const float*)d_in[7];
  const float* a1 = (const float*)d_in[8];
  char* ws = (char*)d_ws;
  f16*   wx  = (f16*)(ws + OFF_WX);
  f16*   h0r = (f16*)(ws + OFF_H0R);
  f16*   h1r = (f16*)(ws + OFF_H1R);
  int*   flg = (int*)(ws + OFF_FLG);
  float* out = (float*)d_out;

  hipMemsetAsync(flg, 0, 32768, stream);           // flags/election start at 0
  k_wx<<<2048, 256, 0, stream>>>(x, W0, b0, wx);   // parallel Wx GEMM

  // 256 blocks: exactly 32 resident per XCD (validated); first 4 XCDs to fill
  // claim groups 0-3; all other blocks exit.
  k_persist<<<256, 256, 0, stream>>>(U0, W1, U1, a0, a1, b1, wx, h0r, h1r, flg, out);
}

// Round 12
// 1032.784 us; speedup vs baseline: 1.2883x; 1.2883x over previous
//
#include <hip/hip_runtime.h>

// Liquid NN: BATCH=64, SEQ=256, IN=512, HID=1024, 2 layers, tau=0.5.
// h0(t) = h0 + a0*2*(tanh(x_t@W0^T + b0 + h0@U0^T) - h0)
// h1(t) = h1 + a1*2*(tanh(h0(t)@W1^T + b1 + h1@U1^T) - h1)
// Output: h1(255) as f32 (64,1024).
//
// R16 = R15 (batch-split + flag-words + stride-68, profiled ~1190us) with the
// Wx PROLOGUE FUSED INTO role0. Bench(1330) - profiled(1190) ~= 140us was the
// serial k_wx kernel + launch gap. W0*x(s) is a third K-stream into role0's
// pre-activation acc: per WG a W0 slice (BfX[4][4] = 64 VGPR, K=128/wave) +
// per-step 16x512 x-slab loads (f32, NO non-temporal: first WG pulls to L2,
// 15 others hit; unique data 32KB/step/group). b0 added in f32 in the
// epilogue. Numerics strictly better than k_wx (no f16 rounding of the wx
// sum). Role0 body grows ~16 MFMA + cvt but keeps 7-step ring slack over
// role1 (the critical chain) -> hidden. Register est ~290 < 512 unified.
// Also: poll s_sleep(2)->(1) (finer detect on the binding flag1 line).
//
// Kept from R15/R13 (validated): 4 groups x 16 rows on 4 XCDs, 256-block grid
// (32/XCD pigeonhole election), depth-8 rings, per-WG FLAG WORDS (publish =
// one relaxed AGENT store, poll = 16-lane vector load of one 64B line,
// per-wave FULL-condition barrier-free polls), no l1_inv (capacity argument),
// fast exp tanh, 16-row XOR LDS reduce map @ stride 68 (bank-uniform).
// Flag algebra (depth-8 rings):
//   role0 s: flag0w[*]>=s (peers s-1), flag1w[*]>=s-7 (ring slot free)
//   role1 t: flag0w[*]>=t+1 (h0(t) ready), flag1w[*]>=t (peers + ring)
//   publish: tid0 stores flagXw[slice]=step+1 AFTER the drain barrier.

typedef _Float16 f16;
typedef _Float16 f16x4 __attribute__((ext_vector_type(4)));
typedef _Float16 f16x8 __attribute__((ext_vector_type(8)));
typedef float    f32x4 __attribute__((ext_vector_type(4)));

#define B_  64
#define S_  256
#define IN_ 512
#define H_  1024
#define GR_ 16   // batch rows per group

static constexpr size_t OFF_H0R = 0;        // 4 groups x 8*16*H f16 = 1048576
static constexpr size_t OFF_H1R = 1048576;  // 4 groups x 8*16*H f16 = 1048576
static constexpr size_t OFF_FLG = 2097152;  // sync area (memset 32768 B)
// flg ints: group g (stride 256 ints = 1KB):
//   flag0w[16] @ g*256 (64B line), flag1w[16] @ g*256+16 (next 64B line)
// election: ecnt[8] @ 1024, xgrp[8] @ 1032

#define AGENT __HIP_MEMORY_SCOPE_AGENT

// ---------------- persistent recurrent kernel (only kernel now) -------------
// dual flag-line poll, per-wave FULL condition: lanes 0-15 wait fA[lane]>=tA,
// lanes 16-31 wait fB[lane&15]>=tB. Each line = one 64B vector load per round
// trip; publishes are plain stores so no RMW serialization.
__device__ __forceinline__ void pollf2(const int* fA, int tA,
                                       const int* fB, int tB, int lane) {
  const bool a = (lane < 16) && (tA > 0);
  const bool b = (lane >= 16) && (lane < 32) && (tB > 0);
  const int* p = a ? (fA + lane) : (fB + (lane & 15));
  const int tgt = a ? tA : tB;
  bool pend = a || b;
  if (pend && __hip_atomic_load((int*)p, __ATOMIC_RELAXED, AGENT) >= tgt)
    pend = false;
  while (__ballot(pend)) {
    __builtin_amdgcn_s_sleep(1);
    if (pend && __hip_atomic_load((int*)p, __ATOMIC_RELAXED, AGENT) >= tgt)
      pend = false;
  }
}

// fast tanh: t = e^{-2|x|} in (0,1], tanh = sign(x)*(1-t)/(1+t). ~1e-7 abs err.
__device__ __forceinline__ float fast_tanh(float x) {
  float t = __expf(-2.0f * fabsf(x));
  float r = (1.0f - t) / (1.0f + t);
  return copysignf(r, x);
}

// 16-row slab: M=16 (one MFMA m-tile), 64 cols, K=256 per wave. ONE batch of
// 8 b128 loads (all in flight immediately) + 32 MFMA.
__device__ __forceinline__ void slab16(const f16* __restrict__ A, int kbase,
                                       int l15, int q,
                                       const f16x8 (&Bf)[4][8], f32x4 (&acc)[4]) {
  f16x8 cur[8];
  const f16* ar = A + (size_t)l15 * H_ + kbase + q * 8;
#pragma unroll
  for (int kf = 0; kf < 8; ++kf) cur[kf] = *(const f16x8*)(ar + kf * 32);
#pragma unroll
  for (int nt = 0; nt < 4; ++nt)
#pragma unroll
    for (int kf = 0; kf < 8; ++kf)
      acc[nt] = __builtin_amdgcn_mfma_f32_16x16x32_f16(cur[kf], Bf[nt][kf],
                                                       acc[nt], 0, 0, 0);
}

__global__ __launch_bounds__(256, 1) void k_persist(
    const float* __restrict__ x,  const float* __restrict__ W0,
    const float* __restrict__ U0, const float* __restrict__ b0,
    const float* __restrict__ W1, const float* __restrict__ U1,
    const float* __restrict__ alpha0, const float* __restrict__ alpha1,
    const float* __restrict__ b1,
    f16* h0r, f16* h1r, int* flg, float* out) {
  // red[ks][i][col]: wave ks's D (16x64) + 4-col pad. i = nt*4 + r,
  // col' = lane ^ (r<<2). Stride 68: reduce-read start bank uniform ->
  // LDS floor (R15: conflicts 6.3M -> 2.1M, now negligible per-step).
  __shared__ __attribute__((aligned(16))) float red[4][16][68];  // 17 KiB
  const int tid = threadIdx.x;
  const int w = tid >> 6, lane = tid & 63;
  const int q = lane >> 4, l15 = lane & 15;

  int* ecnt = flg + 1024;  // per-XCD arrival tickets
  int* xgrp = flg + 1032;  // per-XCD group assignment: 0=pending, g+1, or -1

  // ---- election: 4 XCDs x 32 workers. 256 blocks = exactly 32/XCD resident
  // (validated); block 0 claims the first 4 full XCDs. AGENT scope (cross-XCD).
  const int xcc = (int)__builtin_amdgcn_s_getreg(6164) & 7;  // HW_REG_XCC_ID
  int* sh = (int*)&red[0][0][0];
  if (tid == 0) {
    int my = __hip_atomic_fetch_add(ecnt + xcc, 1, __ATOMIC_RELAXED, AGENT);
    if (blockIdx.x == 0) {
      unsigned taken = 0; int assigned = 0;
      while (assigned < 4) {
        for (int i = 0; i < 8 && assigned < 4; ++i)
          if (!((taken >> i) & 1) &&
              __hip_atomic_load(ecnt + i, __ATOMIC_RELAXED, AGENT) >= 32) {
            taken |= 1u << i;
            __hip_atomic_store(xgrp + i, assigned + 1, __ATOMIC_RELAXED, AGENT);
            ++assigned;
          }
        if (assigned < 4) __builtin_amdgcn_s_sleep(1);
      }
      for (int i = 0; i < 8; ++i)
        if (!((taken >> i) & 1))
          __hip_atomic_store(xgrp + i, -1, __ATOMIC_RELAXED, AGENT);
    }
    int grp = -1;
    if (my < 32) {
      int v;
      while ((v = __hip_atomic_load(xgrp + xcc, __ATOMIC_RELAXED, AGENT)) == 0)
        __builtin_amdgcn_s_sleep(1);
      if (v > 0) grp = v - 1;
    }
    sh[0] = (grp >= 0) ? my : -1;
    sh[1] = grp;
  }
  __syncthreads();
  const int myid = sh[0], g = sh[1];
  __syncthreads();
  if (myid < 0) return;
  const int role = myid >> 4, slice = myid & 15;
  const int c0 = slice * 64;
  const int kbase = w * 256;   // U-slab K-base (K=1024)
  const int kxbase = w * 128;  // W0-slab K-base (K=512), role0 only

  int* flag0w = flg + g * 256;       // word j = steps completed by role0 WG j
  int* flag1w = flg + g * 256 + 16;  // word j = steps completed by role1 WG j
  f16* h0g = h0r + (size_t)g * 8 * GR_ * H_;  // group's depth-8 rings
  f16* h1g = h1r + (size_t)g * 8 * GR_ * H_;

  // ---- weight slices into registers: B[k][n] = Wm[c][k] ----
  f16x8 BfA[4][8];  // role0: U0 ; role1: W1   (K=256/wave)
  f16x8 BfB[4][8];  // role1 only: U1          (K=256/wave)
  f16x8 BfX[4][4];  // role0 only: W0          (K=128/wave)
  {
    const float* WmA = (role == 0) ? U0 : W1;
#pragma unroll
    for (int nt = 0; nt < 4; ++nt)
#pragma unroll
      for (int kf = 0; kf < 8; ++kf) {
        const float* p = WmA + (size_t)(c0 + nt * 16 + l15) * H_ + kbase + kf * 32 + q * 8;
        f16x8 v;
#pragma unroll
        for (int j = 0; j < 8; ++j) v[j] = (f16)p[j];
        BfA[nt][kf] = v;
      }
    if (role == 1) {
#pragma unroll
      for (int nt = 0; nt < 4; ++nt)
#pragma unroll
        for (int kf = 0; kf < 8; ++kf) {
          const float* p = U1 + (size_t)(c0 + nt * 16 + l15) * H_ + kbase + kf * 32 + q * 8;
          f16x8 v;
#pragma unroll
          for (int j = 0; j < 8; ++j) v[j] = (f16)p[j];
          BfB[nt][kf] = v;
        }
    } else {
#pragma unroll
      for (int nt = 0; nt < 4; ++nt)
#pragma unroll
        for (int kf = 0; kf < 4; ++kf) {
          const float* p = W0 + (size_t)(c0 + nt * 16 + l15) * IN_ + kxbase + kf * 32 + q * 8;
          f16x8 v;
#pragma unroll
          for (int j = 0; j < 8; ++j) v[j] = (f16)p[j];
          BfX[nt][kf] = v;
        }
    }
  }

  // ---- epilogue ownership: thread owns (row16, 4 cols) — coalesced stores.
  const int row16 = tid >> 4, cgrp = tid & 15;
  const int iidx  = (cgrp >> 2) * 4 + (row16 & 3);
  const int bcol  = (row16 >> 2) * 16 + ((((cgrp & 3) * 4)) ^ ((row16 & 3) << 2));
  const int coff  = c0 + cgrp * 4;   // global col base of the 4 owned cols
  const int bglob = g * GR_ + row16; // global batch row

  float cf[4], bs[4];
  {
    const float* ap = ((role == 0) ? alpha0 : alpha1) + coff;
    const float* bp = ((role == 0) ? b0 : b1) + coff;
#pragma unroll
    for (int j = 0; j < 4; ++j) { cf[j] = ap[j] * 2.0f; bs[j] = bp[j]; }
  }

  float hst[4] = {0.f, 0.f, 0.f, 0.f};

  if (role == 0) {
    // x-slab base for this wave: row l15 of the group, K-chunk q*8 within
    // [kxbase, kxbase+128). Row stride S_*IN_ (f32).
    const float* xrow = x + ((size_t)(g * GR_ + l15) * S_) * IN_ + kxbase + q * 8;
    for (int s = 0; s < 256; ++s) {
      // x(s) loads issued BEFORE the poll (no dependency): 8 float4/lane,
      // in flight during the poll; L2-shared across the 16 WGs (no NT).
      const float* xb = xrow + (size_t)s * IN_;
      float4 xv[4][2];
#pragma unroll
      for (int kf = 0; kf < 4; ++kf) {
        xv[kf][0] = *(const float4*)(xb + kf * 32);
        xv[kf][1] = *(const float4*)(xb + kf * 32 + 4);
      }
      f32x4 acc[4] = {};
      if (s > 0) {
        // peers' h0(s-1): flag0w[*]>=s ; ring slot s&7 free: flag1w[*]>=s-7
        pollf2(flag0w, s, flag1w, s - 7, lane);
        slab16(h0g + (size_t)((s - 1) & 7) * GR_ * H_, kbase, l15, q, BfA, acc);
      }
      // W0*x(s) into the SAME acc (the pre-activation sum): K=128/wave.
      f16x8 ax[4];
#pragma unroll
      for (int kf = 0; kf < 4; ++kf) {
        f16x8 a;
        const float* v0 = (const float*)&xv[kf][0];
        const float* v1 = (const float*)&xv[kf][1];
#pragma unroll
        for (int j = 0; j < 4; ++j) { a[j] = (f16)v0[j]; a[4 + j] = (f16)v1[j]; }
        ax[kf] = a;
      }
#pragma unroll
      for (int nt = 0; nt < 4; ++nt)
#pragma unroll
        for (int kf = 0; kf < 4; ++kf)
          acc[nt] = __builtin_amdgcn_mfma_f32_16x16x32_f16(ax[kf], BfX[nt][kf],
                                                           acc[nt], 0, 0, 0);
#pragma unroll
      for (int nt = 0; nt < 4; ++nt)
#pragma unroll
        for (int r = 0; r < 4; ++r)
          red[w][nt * 4 + r][lane ^ (r << 2)] = acc[nt][r];
      __syncthreads();
      f32x4 vs = {};
#pragma unroll
      for (int ks = 0; ks < 4; ++ks) {
        f32x4 v = *(const f32x4*)&red[ks][iidx][bcol];
        vs[0] += v[0]; vs[1] += v[1]; vs[2] += v[2]; vs[3] += v[3];
      }
      f16* hw = h0g + (size_t)(s & 7) * GR_ * H_ + (size_t)row16 * H_ + coff;
      f16x4 o;
#pragma unroll
      for (int j = 0; j < 4; ++j) {
        float th = fast_tanh(vs[j] + bs[j]);   // b0 in f32 (was f16 via wx)
        float h = hst[j];
        h = h + cf[j] * (th - h);
        hst[j] = h;
        o[j] = (f16)h;
      }
      *(f16x4*)hw = o;
      __syncthreads();  // drain h stores to L2 + fence red reuse
      if (tid == 0)
        __hip_atomic_store(flag0w + slice, s + 1, __ATOMIC_RELAXED, AGENT);
    }
  } else {
    for (int t = 0; t < 256; ++t) {
      // h0(t) ready: flag0w[*]>=t+1 ; peers' h1(t-1) + ring: flag1w[*]>=t
      pollf2(flag0w, t + 1, flag1w, t, lane);
      f32x4 acc[4] = {};
      // both A batches issued up front (16 b128 in flight), then MFMAs.
      f16x8 cA[8], cB[8];
      const f16* a0 = h0g + (size_t)(t & 7) * GR_ * H_ + (size_t)l15 * H_ + kbase + q * 8;
#pragma unroll
      for (int kf = 0; kf < 8; ++kf) cA[kf] = *(const f16x8*)(a0 + kf * 32);
      if (t > 0) {
        const f16* a1 = h1g + (size_t)((t - 1) & 7) * GR_ * H_ + (size_t)l15 * H_ + kbase + q * 8;
#pragma unroll
        for (int kf = 0; kf < 8; ++kf) cB[kf] = *(const f16x8*)(a1 + kf * 32);
      }
#pragma unroll
      for (int nt = 0; nt < 4; ++nt)
#pragma unroll
        for (int kf = 0; kf < 8; ++kf)
          acc[nt] = __builtin_amdgcn_mfma_f32_16x16x32_f16(cA[kf], BfA[nt][kf],
                                                           acc[nt], 0, 0, 0);
      if (t > 0) {
#pragma unroll
        for (int nt = 0; nt < 4; ++nt)
#pragma unroll
          for (int kf = 0; kf < 8; ++kf)
            acc[nt] = __builtin_amdgcn_mfma_f32_16x16x32_f16(cB[kf], BfB[nt][kf],
                                                             acc[nt], 0, 0, 0);
      }
#pragma unroll
      for (int nt = 0; nt < 4; ++nt)
#pragma unroll
        for (int r = 0; r < 4; ++r)
          red[w][nt * 4 + r][lane ^ (r << 2)] = acc[nt][r];
      __syncthreads();
      f32x4 vs = {};
#pragma unroll
      for (int ks = 0; ks < 4; ++ks) {
        f32x4 v = *(const f32x4*)&red[ks][iidx][bcol];
        vs[0] += v[0]; vs[1] += v[1]; vs[2] += v[2]; vs[3] += v[3];
      }
      f16* hw = h1g + (size_t)(t & 7) * GR_ * H_ + (size_t)row16 * H_ + coff;
      f16x4 o;
#pragma unroll
      for (int j = 0; j < 4; ++j) {
        float th = fast_tanh(vs[j] + bs[j]);
        float h = hst[j];
        h = h + cf[j] * (th - h);
        hst[j] = h;
        o[j] = (f16)h;
      }
      *(f16x4*)hw = o;
      if (t == 255) {
        float* op = out + (size_t)bglob * H_ + coff;
        float4 vv;
        vv.x = hst[0]; vv.y = hst[1]; vv.z = hst[2]; vv.w = hst[3];
        *(float4*)op = vv;
      }
      __syncthreads();  // drain h1 stores + fence red reuse
      if (tid == 0)
        __hip_atomic_store(flag1w + slice, t + 1, __ATOMIC_RELAXED, AGENT);
    }
  }
}

// LDS map identity (16-row variant): writer wave ks, lane = q*16+l15 stores
// D[m][n] (m=q*4+r, n=nt*16+l15) at red[ks][nt*4+r][(q*16+l15)^(r<<2)].
// Reader (row16,cgrp) wants (m=row16, n=cgrp*4+j): r=row16&3, nt=cgrp>>2,
// q=row16>>2, l15=(cgrp&3)*4+j -> i=nt*4+r, col'=q*16+(((cgrp&3)*4+j)^(r<<2)).
// XOR touches bits 2-3 only, j lives in bits 0-1 -> col' = bcol + j: one
// aligned f32x4 read. (row16,cgrp)->(i,bcol) is bijective over 256 threads.
// Stride 68: read start-bank uniform over lanes -> LDS-floor, ~0 conflicts.

extern "C" void kernel_launch(void* const* d_in, const int* in_sizes, int n_in,
                              void* d_out, int out_size, void* d_ws, size_t ws_size,
                              hipStream_t stream) {
  const float* x  = (const float*)d_in[0];
  const float* W0 = (const float*)d_in[1];
  const float* U0 = (const float*)d_in[2];
  const float* b0 = (const float*)d_in[3];
  const float* a0 = (const float*)d_in[4];
  const float* W1 = (const float*)d_in[5];
  const float* U1 = (const float*)d_in[6];
  const float* b1 = (const float*)d_in[7];
  const float* a1 = (const float*)d_in[8];
  char* ws = (char*)d_ws;
  f16*   h0r = (f16*)(ws + OFF_H0R);
  f16*   h1r = (f16*)(ws + OFF_H1R);
  int*   flg = (int*)(ws + OFF_FLG);
  float* out = (float*)d_out;

  hipMemsetAsync(flg, 0, 32768, stream);  // flags/election start at 0

  // Single persistent kernel (Wx fused into role0). 256 blocks: exactly 32
  // resident per XCD (validated); first 4 XCDs to fill claim groups 0-3;
  // all other blocks exit.
  k_persist<<<256, 256, 0, stream>>>(x, W0, U0, b0, W1, U1, a0, a1, b1,
                                     h0r, h1r, flg, out);
}